// Round 7
// baseline (46.994 us; speedup 1.0000x reference)
//
#include <hip/hip_runtime.h>
#include <math.h>

// GaussianMixtureLoss: loss = CONST - mean_{b,n}( ln sum_m exp(p·g - |g|²/2) - |p|²/2 )
// B=4, N=4096, M=4096, D=3, SIGMA=1.
// R7: MEASUREMENT ROUND. K1/K2 byte-identical to R6; gm_main launched 3x
// (idempotent). dur = 3*K1 + K2 + OH resolves K1 vs fixed overhead.
#define BATCH 4
#define NPTS 4096
#define NMIX 4096
#define THREADS 256
#define PPB 16                // points per block
#define PPT 8                 // points per thread (4x v2f)
#define SCH 128               // mixture chunks per block (PPB/PPT * SCH = 256)
#define MSTAGE 2048           // mixtures staged per pass (32 KB)
#define PASSES (NMIX / MSTAGE)
#define MPT (MSTAGE / SCH)    // 16 mixtures per thread per pass
#define NBLOCKS ((BATCH * NPTS) / PPB)  // 1024

#define L2E 1.4426950408889634f
#define LN2 0.6931471805599453f
#define CONST_TERM 0.9189385332046727f  // 0.5*log(2*pi)
#define INV_COUNT (1.0f / (float)(BATCH * NPTS))

typedef float v2f __attribute__((ext_vector_type(2)));

__device__ __forceinline__ float fast_exp2(float x) {
#if __has_builtin(__builtin_amdgcn_exp2f)
  return __builtin_amdgcn_exp2f(x);   // raw v_exp_f32
#else
  return exp2f(x);
#endif
}
__device__ __forceinline__ float fast_log2(float x) {
#if __has_builtin(__builtin_amdgcn_logf)
  return __builtin_amdgcn_logf(x);    // raw v_log_f32
#else
  return log2f(x);
#endif
}

__global__ __launch_bounds__(THREADS) void gm_main(
    const float* __restrict__ pred, const float* __restrict__ gt,
    float* __restrict__ bsum) {
  __shared__ float4 gsh[MSTAGE];   // 32 KB: (L2E*g, -0.5*L2E*|g|^2)
  __shared__ float wpart[64];      // [4 waves][16 points]
  float* comb = (float*)gsh;       // aliased tail buffer [SCH][PPB+1]=[128][17]

  const int t = threadIdx.x;
  const int b = blockIdx.x >> 8;             // 256 blocks per batch
  const int n0 = (blockIdx.x & 255) * PPB;
  const int c = t >> 1;                      // mixture chunk 0..127
  const int pi = (t & 1) * PPT;              // point base 0 or 8

  // 8 points as 4 v2f packs (adjacent points are contiguous: 6 floats)
  v2f px[4], py[4], pz[4], acc[4];
#pragma unroll
  for (int k = 0; k < 4; ++k) {
    const float* p = pred + ((size_t)(b * NPTS + n0 + pi + 2 * k)) * 3;
    px[k] = (v2f){p[0], p[3]};
    py[k] = (v2f){p[1], p[4]};
    pz[k] = (v2f){p[2], p[5]};
    acc[k] = (v2f){0.f, 0.f};
  }

  for (int q = 0; q < PASSES; ++q) {
    __syncthreads();  // prior-pass readers done before restage
#pragma unroll
    for (int k2 = 0; k2 < MSTAGE / THREADS; ++k2) {
      int s = t + k2 * THREADS;
      const float* g = gt + ((size_t)(b * NMIX + q * MSTAGE + s)) * 3;
      float gx = g[0], gy = g[1], gz = g[2];
      gsh[s] = make_float4(L2E * gx, L2E * gy, L2E * gz,
                           -0.5f * L2E * (gx * gx + gy * gy + gz * gz));
    }
    __syncthreads();

    const float4* gp = gsh + c * MPT;
#pragma unroll 4
    for (int j = 0; j < MPT; ++j) {
      float4 gv = gp[j];  // 1 ds_read_b128 serves 8 exps
      v2f bx = {gv.x, gv.x}, by = {gv.y, gv.y};
      v2f bz = {gv.z, gv.z}, bw = {gv.w, gv.w};
#pragma unroll
      for (int k = 0; k < 4; ++k) {
        v2f d = __builtin_elementwise_fma(px[k], bx,
                __builtin_elementwise_fma(py[k], by,
                __builtin_elementwise_fma(pz[k], bz, bw)));
        acc[k].x += fast_exp2(d.x);
        acc[k].y += fast_exp2(d.y);
      }
    }
  }

  __syncthreads();  // all gsh reads done before aliasing as comb

  // comb[c][pi+j]: strided write, worst 2-way bank alias (free)
#pragma unroll
  for (int k = 0; k < 4; ++k) {
    comb[c * (PPB + 1) + pi + 2 * k]     = acc[k].x;
    comb[c * (PPB + 1) + pi + 2 * k + 1] = acc[k].y;
  }
  __syncthreads();

  // thread t: point p = t&15, chunk-group g = t>>4 (8 chunks each)
  {
    const int p = t & 15, g = t >> 4;
    float s = 0.f;
#pragma unroll
    for (int j = 0; j < 8; ++j) s += comb[(g * 8 + j) * (PPB + 1) + p];
    // reduce across the 4 chunk-groups within this wave (lanes p, p+16, ...)
    s += __shfl_down(s, 32, 64);
    s += __shfl_down(s, 16, 64);
    if ((t & 63) < 16) wpart[(t >> 6) * 16 + (t & 15)] = s;
  }
  __syncthreads();

  if (t < 16) {
    float s = wpart[t] + wpart[16 + t] + wpart[32 + t] + wpart[48 + t];
    const float* p = pred + ((size_t)(b * NPTS + n0 + t)) * 3;
    float hp2 = 0.5f * (p[0] * p[0] + p[1] * p[1] + p[2] * p[2]);
    float ll = (LN2 * fast_log2(s) - hp2) * INV_COUNT;
#pragma unroll
    for (int off = 8; off > 0; off >>= 1) ll += __shfl_down(ll, off, 16);
    if (t == 0) bsum[blockIdx.x] = ll;
  }
}

__global__ __launch_bounds__(THREADS) void gm_reduce(
    const float* __restrict__ bsum, float* __restrict__ out) {
  const int t = threadIdx.x;
  float v = (bsum[t] + bsum[t + 256]) + (bsum[t + 512] + bsum[t + 768]);
  for (int off = 32; off > 0; off >>= 1) v += __shfl_down(v, off, 64);
  __shared__ float w[4];
  if ((t & 63) == 0) w[t >> 6] = v;
  __syncthreads();
  if (t == 0) out[0] = CONST_TERM - ((w[0] + w[1]) + (w[2] + w[3]));
}

extern "C" void kernel_launch(void* const* d_in, const int* in_sizes, int n_in,
                              void* d_out, int out_size, void* d_ws, size_t ws_size,
                              hipStream_t stream) {
  const float* pred = (const float*)d_in[0];
  const float* gt   = (const float*)d_in[1];
  float* out = (float*)d_out;
  float* bsum = (float*)d_ws;  // 1024 floats, fully overwritten every call

  // PROBE: 3 identical launches (idempotent writes) to resolve
  // K1 duration vs fixed graph overhead: dur = 3*K1 + K2 + OH.
  gm_main<<<NBLOCKS, THREADS, 0, stream>>>(pred, gt, bsum);
  gm_main<<<NBLOCKS, THREADS, 0, stream>>>(pred, gt, bsum);
  gm_main<<<NBLOCKS, THREADS, 0, stream>>>(pred, gt, bsum);

  gm_reduce<<<1, THREADS, 0, stream>>>(bsum, out);
}

// Round 8
// 25.321 us; speedup vs baseline: 1.8560x; 1.8560x over previous
//
#include <hip/hip_runtime.h>
#include <math.h>

// GaussianMixtureLoss: loss = CONST - mean_{b,n}( ln sum_m exp(p·g - |g|²/2) - |p|²/2 )
// B=4, N=4096, M=4096, D=3, SIGMA=1.
// R8: hybrid exp — half the exponentials on the trans pipe (v_exp_f32,
// measured ~32 cyc/wave64 on gfx950 = the R1..R7 floor), half as a deg-4
// polynomial on the full-rate VALU pipe, so the two pipes overlap.
// Structure otherwise identical to R6: 1024 blocks, block = 16 pts x 4096
// mixtures, thread = 8 pts (v2f packed dot), 2 LDS passes, no atomics.
#define BATCH 4
#define NPTS 4096
#define NMIX 4096
#define THREADS 256
#define PPB 16                // points per block
#define PPT 8                 // points per thread (4x v2f)
#define SCH 128               // mixture chunks per block
#define MSTAGE 2048           // mixtures staged per pass (32 KB)
#define PASSES (NMIX / MSTAGE)
#define MPT (MSTAGE / SCH)    // 16 mixtures per thread per pass
#define NBLOCKS ((BATCH * NPTS) / PPB)  // 1024

#define L2E 1.4426950408889634f
#define LN2 0.6931471805599453f
#define CONST_TERM 0.9189385332046727f  // 0.5*log(2*pi)
#define INV_COUNT (1.0f / (float)(BATCH * NPTS))

typedef float v2f __attribute__((ext_vector_type(2)));

__device__ __forceinline__ float fast_exp2(float x) {
#if __has_builtin(__builtin_amdgcn_exp2f)
  return __builtin_amdgcn_exp2f(x);   // raw v_exp_f32 (trans pipe)
#else
  return exp2f(x);
#endif
}
__device__ __forceinline__ float fast_log2(float x) {
#if __has_builtin(__builtin_amdgcn_logf)
  return __builtin_amdgcn_logf(x);    // raw v_log_f32
#else
  return log2f(x);
#endif
}

// Full-rate VALU exp2: 2^x = 2^n * 2^f, n=rndne(x), f=x-n in [-0.5,0.5].
// Deg-4 poly rel err ~1e-5; ldexp handles scaling incl. graceful underflow.
__device__ __forceinline__ float poly_exp2(float x) {
  float n = __builtin_rintf(x);                 // v_rndne_f32
  float f = x - n;
  float p = fmaf(f, 0.0096181291f, 0.0555041087f);
  p = fmaf(f, p, 0.2402265069f);
  p = fmaf(f, p, 0.6931471806f);
  p = fmaf(f, p, 1.0f);
#if __has_builtin(__builtin_amdgcn_ldexpf)
  return __builtin_amdgcn_ldexpf(p, (int)n);    // v_ldexp_f32
#else
  return ldexpf(p, (int)n);
#endif
}

__global__ __launch_bounds__(THREADS) void gm_main(
    const float* __restrict__ pred, const float* __restrict__ gt,
    float* __restrict__ bsum) {
  __shared__ float4 gsh[MSTAGE];   // 32 KB: (L2E*g, -0.5*L2E*|g|^2)
  __shared__ float wpart[64];      // [4 waves][16 points]
  float* comb = (float*)gsh;       // aliased tail buffer [SCH][PPB+1]

  const int t = threadIdx.x;
  const int b = blockIdx.x >> 8;             // 256 blocks per batch
  const int n0 = (blockIdx.x & 255) * PPB;
  const int c = t >> 1;                      // mixture chunk 0..127
  const int pi = (t & 1) * PPT;              // point base 0 or 8

  v2f px[4], py[4], pz[4], acc[4];
#pragma unroll
  for (int k = 0; k < 4; ++k) {
    const float* p = pred + ((size_t)(b * NPTS + n0 + pi + 2 * k)) * 3;
    px[k] = (v2f){p[0], p[3]};
    py[k] = (v2f){p[1], p[4]};
    pz[k] = (v2f){p[2], p[5]};
    acc[k] = (v2f){0.f, 0.f};
  }

  for (int q = 0; q < PASSES; ++q) {
    __syncthreads();
#pragma unroll
    for (int k2 = 0; k2 < MSTAGE / THREADS; ++k2) {
      int s = t + k2 * THREADS;
      const float* g = gt + ((size_t)(b * NMIX + q * MSTAGE + s)) * 3;
      float gx = g[0], gy = g[1], gz = g[2];
      gsh[s] = make_float4(L2E * gx, L2E * gy, L2E * gz,
                           -0.5f * L2E * (gx * gx + gy * gy + gz * gz));
    }
    __syncthreads();

    const float4* gp = gsh + c * MPT;
#pragma unroll 4
    for (int j = 0; j < MPT; ++j) {
      float4 gv = gp[j];  // 1 ds_read_b128 serves 8 exps
      v2f bx = {gv.x, gv.x}, by = {gv.y, gv.y};
      v2f bz = {gv.z, gv.z}, bw = {gv.w, gv.w};
      // k=0,1 -> trans pipe; k=2,3 -> VALU poly (pipes overlap across waves)
#pragma unroll
      for (int k = 0; k < 2; ++k) {
        v2f d = __builtin_elementwise_fma(px[k], bx,
                __builtin_elementwise_fma(py[k], by,
                __builtin_elementwise_fma(pz[k], bz, bw)));
        acc[k].x += fast_exp2(d.x);
        acc[k].y += fast_exp2(d.y);
      }
#pragma unroll
      for (int k = 2; k < 4; ++k) {
        v2f d = __builtin_elementwise_fma(px[k], bx,
                __builtin_elementwise_fma(py[k], by,
                __builtin_elementwise_fma(pz[k], bz, bw)));
        acc[k].x += poly_exp2(d.x);
        acc[k].y += poly_exp2(d.y);
      }
    }
  }

  __syncthreads();  // all gsh reads done before aliasing as comb

#pragma unroll
  for (int k = 0; k < 4; ++k) {
    comb[c * (PPB + 1) + pi + 2 * k]     = acc[k].x;
    comb[c * (PPB + 1) + pi + 2 * k + 1] = acc[k].y;
  }
  __syncthreads();

  {
    const int p = t & 15, g = t >> 4;
    float s = 0.f;
#pragma unroll
    for (int j = 0; j < 8; ++j) s += comb[(g * 8 + j) * (PPB + 1) + p];
    s += __shfl_down(s, 32, 64);
    s += __shfl_down(s, 16, 64);
    if ((t & 63) < 16) wpart[(t >> 6) * 16 + (t & 15)] = s;
  }
  __syncthreads();

  if (t < 16) {
    float s = wpart[t] + wpart[16 + t] + wpart[32 + t] + wpart[48 + t];
    const float* p = pred + ((size_t)(b * NPTS + n0 + t)) * 3;
    float hp2 = 0.5f * (p[0] * p[0] + p[1] * p[1] + p[2] * p[2]);
    float ll = (LN2 * fast_log2(s) - hp2) * INV_COUNT;
#pragma unroll
    for (int off = 8; off > 0; off >>= 1) ll += __shfl_down(ll, off, 16);
    if (t == 0) bsum[blockIdx.x] = ll;
  }
}

__global__ __launch_bounds__(THREADS) void gm_reduce(
    const float* __restrict__ bsum, float* __restrict__ out) {
  const int t = threadIdx.x;
  float v = (bsum[t] + bsum[t + 256]) + (bsum[t + 512] + bsum[t + 768]);
  for (int off = 32; off > 0; off >>= 1) v += __shfl_down(v, off, 64);
  __shared__ float w[4];
  if ((t & 63) == 0) w[t >> 6] = v;
  __syncthreads();
  if (t == 0) out[0] = CONST_TERM - ((w[0] + w[1]) + (w[2] + w[3]));
}

extern "C" void kernel_launch(void* const* d_in, const int* in_sizes, int n_in,
                              void* d_out, int out_size, void* d_ws, size_t ws_size,
                              hipStream_t stream) {
  const float* pred = (const float*)d_in[0];
  const float* gt   = (const float*)d_in[1];
  float* out = (float*)d_out;
  float* bsum = (float*)d_ws;  // 1024 floats, fully overwritten every call

  gm_main<<<NBLOCKS, THREADS, 0, stream>>>(pred, gt, bsum);
  gm_reduce<<<1, THREADS, 0, stream>>>(bsum, out);
}

// Round 9
// 20.481 us; speedup vs baseline: 2.2946x; 1.2363x over previous
//
#include <hip/hip_runtime.h>
#include <math.h>

// GaussianMixtureLoss: loss = CONST - mean_{b,n}( ln sum_m exp(p·g - |g|²/2) - |p|²/2 )
// B=4, N=4096, M=4096, D=3, SIGMA=1.
// R9: Schraudolph exp2 — all 67.1M exponentials on the full-rate VALU pipe:
//   2^x ~= bitcast((int)(2^23*(x + 127 - 0.0563)))   [zero-mean log error,
//   max +-5.6% per term, ~+-1.3% softmax-weighted per point, ~0.005 on loss]
// v_exp_f32 measured ~32cyc/wave64 (R7 probe) was the R1..R6 floor; this is
// fma+max+cvt+add ~= 8 cyc. Structure otherwise identical to R6:
// 1024 blocks, block = 16 pts x 4096 mixtures, thread = 8 pts (v2f dot),
// 2 LDS passes, aliased LDS tail, no atomics, no ws init.
#define BATCH 4
#define NPTS 4096
#define NMIX 4096
#define THREADS 256
#define PPB 16                // points per block
#define PPT 8                 // points per thread (4x v2f)
#define SCH 128               // mixture chunks per block
#define MSTAGE 2048           // mixtures staged per pass (32 KB)
#define PASSES (NMIX / MSTAGE)
#define MPT (MSTAGE / SCH)    // 16 mixtures per thread per pass
#define NBLOCKS ((BATCH * NPTS) / PPB)  // 1024

#define L2E 1.4426950408889634f
#define LN2 0.6931471805599453f
#define CONST_TERM 0.9189385332046727f  // 0.5*log(2*pi)
#define INV_COUNT (1.0f / (float)(BATCH * NPTS))
// Schraudolph: 2^23 * (127 - 0.0563) ; zero-mean log-domain error
#define SEXP_SCALE 8388608.0f
#define SEXP_BIAS  1.06488094e9f

typedef float v2f __attribute__((ext_vector_type(2)));

__device__ __forceinline__ float fast_log2(float x) {
#if __has_builtin(__builtin_amdgcn_logf)
  return __builtin_amdgcn_logf(x);    // raw v_log_f32 (only 16K of these)
#else
  return log2f(x);
#endif
}

// packed Schraudolph exp2 on 2 lanes: pk_fma + pk_max + 2x cvt (+bitcast free)
__device__ __forceinline__ v2f sexp2_v2(v2f x) {
  v2f t = __builtin_elementwise_fma(
      x, (v2f){SEXP_SCALE, SEXP_SCALE}, (v2f){SEXP_BIAS, SEXP_BIAS});
  t = __builtin_elementwise_max(t, (v2f){0.f, 0.f});  // underflow -> +0.0
  int ix = (int)t.x, iy = (int)t.y;
  v2f r;
  r.x = __builtin_bit_cast(float, ix);
  r.y = __builtin_bit_cast(float, iy);
  return r;
}

__global__ __launch_bounds__(THREADS) void gm_main(
    const float* __restrict__ pred, const float* __restrict__ gt,
    float* __restrict__ bsum) {
  __shared__ float4 gsh[MSTAGE];   // 32 KB: (L2E*g, -0.5*L2E*|g|^2)
  __shared__ float wpart[64];      // [4 waves][16 points]
  float* comb = (float*)gsh;       // aliased tail buffer [SCH][PPB+1]

  const int t = threadIdx.x;
  const int b = blockIdx.x >> 8;             // 256 blocks per batch
  const int n0 = (blockIdx.x & 255) * PPB;
  const int c = t >> 1;                      // mixture chunk 0..127
  const int pi = (t & 1) * PPT;              // point base 0 or 8

  v2f px[4], py[4], pz[4], acc[4];
#pragma unroll
  for (int k = 0; k < 4; ++k) {
    const float* p = pred + ((size_t)(b * NPTS + n0 + pi + 2 * k)) * 3;
    px[k] = (v2f){p[0], p[3]};
    py[k] = (v2f){p[1], p[4]};
    pz[k] = (v2f){p[2], p[5]};
    acc[k] = (v2f){0.f, 0.f};
  }

  for (int q = 0; q < PASSES; ++q) {
    __syncthreads();
#pragma unroll
    for (int k2 = 0; k2 < MSTAGE / THREADS; ++k2) {
      int s = t + k2 * THREADS;
      const float* g = gt + ((size_t)(b * NMIX + q * MSTAGE + s)) * 3;
      float gx = g[0], gy = g[1], gz = g[2];
      gsh[s] = make_float4(L2E * gx, L2E * gy, L2E * gz,
                           -0.5f * L2E * (gx * gx + gy * gy + gz * gz));
    }
    __syncthreads();

    const float4* gp = gsh + c * MPT;
#pragma unroll 2
    for (int j = 0; j < MPT; ++j) {
      float4 gv = gp[j];  // 1 ds_read_b128 serves 8 exps
      v2f bx = {gv.x, gv.x}, by = {gv.y, gv.y};
      v2f bz = {gv.z, gv.z}, bw = {gv.w, gv.w};
#pragma unroll
      for (int k = 0; k < 4; ++k) {
        v2f d = __builtin_elementwise_fma(px[k], bx,
                __builtin_elementwise_fma(py[k], by,
                __builtin_elementwise_fma(pz[k], bz, bw)));
        acc[k] += sexp2_v2(d);
      }
    }
  }

  __syncthreads();  // all gsh reads done before aliasing as comb

#pragma unroll
  for (int k = 0; k < 4; ++k) {
    comb[c * (PPB + 1) + pi + 2 * k]     = acc[k].x;
    comb[c * (PPB + 1) + pi + 2 * k + 1] = acc[k].y;
  }
  __syncthreads();

  {
    const int p = t & 15, g = t >> 4;
    float s = 0.f;
#pragma unroll
    for (int j = 0; j < 8; ++j) s += comb[(g * 8 + j) * (PPB + 1) + p];
    s += __shfl_down(s, 32, 64);
    s += __shfl_down(s, 16, 64);
    if ((t & 63) < 16) wpart[(t >> 6) * 16 + (t & 15)] = s;
  }
  __syncthreads();

  if (t < 16) {
    float s = wpart[t] + wpart[16 + t] + wpart[32 + t] + wpart[48 + t];
    const float* p = pred + ((size_t)(b * NPTS + n0 + t)) * 3;
    float hp2 = 0.5f * (p[0] * p[0] + p[1] * p[1] + p[2] * p[2]);
    float ll = (LN2 * fast_log2(s) - hp2) * INV_COUNT;
#pragma unroll
    for (int off = 8; off > 0; off >>= 1) ll += __shfl_down(ll, off, 16);
    if (t == 0) bsum[blockIdx.x] = ll;
  }
}

__global__ __launch_bounds__(THREADS) void gm_reduce(
    const float* __restrict__ bsum, float* __restrict__ out) {
  const int t = threadIdx.x;
  float v = (bsum[t] + bsum[t + 256]) + (bsum[t + 512] + bsum[t + 768]);
  for (int off = 32; off > 0; off >>= 1) v += __shfl_down(v, off, 64);
  __shared__ float w[4];
  if ((t & 63) == 0) w[t >> 6] = v;
  __syncthreads();
  if (t == 0) out[0] = CONST_TERM - ((w[0] + w[1]) + (w[2] + w[3]));
}

extern "C" void kernel_launch(void* const* d_in, const int* in_sizes, int n_in,
                              void* d_out, int out_size, void* d_ws, size_t ws_size,
                              hipStream_t stream) {
  const float* pred = (const float*)d_in[0];
  const float* gt   = (const float*)d_in[1];
  float* out = (float*)d_out;
  float* bsum = (float*)d_ws;  // 1024 floats, fully overwritten every call

  gm_main<<<NBLOCKS, THREADS, 0, stream>>>(pred, gt, bsum);
  gm_reduce<<<1, THREADS, 0, stream>>>(bsum, out);
}

// Round 10
// 19.792 us; speedup vs baseline: 2.3744x; 1.0348x over previous
//
#include <hip/hip_runtime.h>
#include <math.h>

// GaussianMixtureLoss: loss = CONST - mean_{b,n}( ln sum_m exp(p·g - |g|²/2) - |p|²/2 )
// B=4, N=4096, M=4096, D=3, SIGMA=1.
// R10: fix the 32-way LDS bank conflict that pinned R5..R9 at ~13.5us.
//   Old map: thread pair c reads gsh[c*16 + j]  -> lane-pair stride 256 B
//            -> bank-step 0 -> 32-way conflict on EVERY inner ds_read_b128.
//   New map: thread pair c reads gsh[c + 128*j] -> wave reads 32 consecutive
//            float4s (512 B contiguous) -> conflict-free (2-way pair
//            broadcast is free per m136).
// Everything else byte-identical to R9 (Schraudolph exp on VALU pipe,
// 1024 blocks, 16 pts x 4096 mix per block, 2 LDS passes, no atomics).
#define BATCH 4
#define NPTS 4096
#define NMIX 4096
#define THREADS 256
#define PPB 16                // points per block
#define PPT 8                 // points per thread (4x v2f)
#define SCH 128               // mixture chunks per block
#define MSTAGE 2048           // mixtures staged per pass (32 KB)
#define PASSES (NMIX / MSTAGE)
#define MPT (MSTAGE / SCH)    // 16 mixtures per thread per pass
#define NBLOCKS ((BATCH * NPTS) / PPB)  // 1024

#define L2E 1.4426950408889634f
#define LN2 0.6931471805599453f
#define CONST_TERM 0.9189385332046727f  // 0.5*log(2*pi)
#define INV_COUNT (1.0f / (float)(BATCH * NPTS))
// Schraudolph: 2^23 * (127 - 0.0563) ; zero-mean log-domain error
#define SEXP_SCALE 8388608.0f
#define SEXP_BIAS  1.06488094e9f

typedef float v2f __attribute__((ext_vector_type(2)));

__device__ __forceinline__ float fast_log2(float x) {
#if __has_builtin(__builtin_amdgcn_logf)
  return __builtin_amdgcn_logf(x);    // raw v_log_f32 (only 16K of these)
#else
  return log2f(x);
#endif
}

// packed Schraudolph exp2 on 2 lanes: pk_fma + pk_max + 2x cvt (+bitcast free)
__device__ __forceinline__ v2f sexp2_v2(v2f x) {
  v2f t = __builtin_elementwise_fma(
      x, (v2f){SEXP_SCALE, SEXP_SCALE}, (v2f){SEXP_BIAS, SEXP_BIAS});
  t = __builtin_elementwise_max(t, (v2f){0.f, 0.f});  // underflow -> +0.0
  int ix = (int)t.x, iy = (int)t.y;
  v2f r;
  r.x = __builtin_bit_cast(float, ix);
  r.y = __builtin_bit_cast(float, iy);
  return r;
}

__global__ __launch_bounds__(THREADS) void gm_main(
    const float* __restrict__ pred, const float* __restrict__ gt,
    float* __restrict__ bsum) {
  __shared__ float4 gsh[MSTAGE];   // 32 KB: (L2E*g, -0.5*L2E*|g|^2)
  __shared__ float wpart[64];      // [4 waves][16 points]
  float* comb = (float*)gsh;       // aliased tail buffer [SCH][PPB+1]

  const int t = threadIdx.x;
  const int b = blockIdx.x >> 8;             // 256 blocks per batch
  const int n0 = (blockIdx.x & 255) * PPB;
  const int c = t >> 1;                      // mixture lane-pair 0..127
  const int pi = (t & 1) * PPT;              // point base 0 or 8

  v2f px[4], py[4], pz[4], acc[4];
#pragma unroll
  for (int k = 0; k < 4; ++k) {
    const float* p = pred + ((size_t)(b * NPTS + n0 + pi + 2 * k)) * 3;
    px[k] = (v2f){p[0], p[3]};
    py[k] = (v2f){p[1], p[4]};
    pz[k] = (v2f){p[2], p[5]};
    acc[k] = (v2f){0.f, 0.f};
  }

  for (int q = 0; q < PASSES; ++q) {
    __syncthreads();
#pragma unroll
    for (int k2 = 0; k2 < MSTAGE / THREADS; ++k2) {
      int s = t + k2 * THREADS;
      const float* g = gt + ((size_t)(b * NMIX + q * MSTAGE + s)) * 3;
      float gx = g[0], gy = g[1], gz = g[2];
      gsh[s] = make_float4(L2E * gx, L2E * gy, L2E * gz,
                           -0.5f * L2E * (gx * gx + gy * gy + gz * gz));
    }
    __syncthreads();

#pragma unroll 2
    for (int j = 0; j < MPT; ++j) {
      // interleaved map: wave reads 32 consecutive float4s -> conflict-free
      float4 gv = gsh[c + SCH * j];
      v2f bx = {gv.x, gv.x}, by = {gv.y, gv.y};
      v2f bz = {gv.z, gv.z}, bw = {gv.w, gv.w};
#pragma unroll
      for (int k = 0; k < 4; ++k) {
        v2f d = __builtin_elementwise_fma(px[k], bx,
                __builtin_elementwise_fma(py[k], by,
                __builtin_elementwise_fma(pz[k], bz, bw)));
        acc[k] += sexp2_v2(d);
      }
    }
  }

  __syncthreads();  // all gsh reads done before aliasing as comb

#pragma unroll
  for (int k = 0; k < 4; ++k) {
    comb[c * (PPB + 1) + pi + 2 * k]     = acc[k].x;
    comb[c * (PPB + 1) + pi + 2 * k + 1] = acc[k].y;
  }
  __syncthreads();

  {
    const int p = t & 15, g = t >> 4;
    float s = 0.f;
#pragma unroll
    for (int j = 0; j < 8; ++j) s += comb[(g * 8 + j) * (PPB + 1) + p];
    s += __shfl_down(s, 32, 64);
    s += __shfl_down(s, 16, 64);
    if ((t & 63) < 16) wpart[(t >> 6) * 16 + (t & 15)] = s;
  }
  __syncthreads();

  if (t < 16) {
    float s = wpart[t] + wpart[16 + t] + wpart[32 + t] + wpart[48 + t];
    const float* p = pred + ((size_t)(b * NPTS + n0 + t)) * 3;
    float hp2 = 0.5f * (p[0] * p[0] + p[1] * p[1] + p[2] * p[2]);
    float ll = (LN2 * fast_log2(s) - hp2) * INV_COUNT;
#pragma unroll
    for (int off = 8; off > 0; off >>= 1) ll += __shfl_down(ll, off, 16);
    if (t == 0) bsum[blockIdx.x] = ll;
  }
}

__global__ __launch_bounds__(THREADS) void gm_reduce(
    const float* __restrict__ bsum, float* __restrict__ out) {
  const int t = threadIdx.x;
  float v = (bsum[t] + bsum[t + 256]) + (bsum[t + 512] + bsum[t + 768]);
  for (int off = 32; off > 0; off >>= 1) v += __shfl_down(v, off, 64);
  __shared__ float w[4];
  if ((t & 63) == 0) w[t >> 6] = v;
  __syncthreads();
  if (t == 0) out[0] = CONST_TERM - ((w[0] + w[1]) + (w[2] + w[3]));
}

extern "C" void kernel_launch(void* const* d_in, const int* in_sizes, int n_in,
                              void* d_out, int out_size, void* d_ws, size_t ws_size,
                              hipStream_t stream) {
  const float* pred = (const float*)d_in[0];
  const float* gt   = (const float*)d_in[1];
  float* out = (float*)d_out;
  float* bsum = (float*)d_ws;  // 1024 floats, fully overwritten every call

  gm_main<<<NBLOCKS, THREADS, 0, stream>>>(pred, gt, bsum);
  gm_reduce<<<1, THREADS, 0, stream>>>(bsum, out);
}